// Round 4
// baseline (39.843 us; speedup 1.0000x reference)
//
#include <hip/hip_runtime.h>
#include <hip/hip_bf16.h>

#define Bn 16
#define Sn 2048
#define Hn 768
#define Dn 128
#define AT 8
#define IT 32
#define NSEG (Bn*AT*IT)      // 4096

typedef __attribute__((ext_vector_type(4))) float f32x4;
typedef __attribute__((ext_vector_type(4))) int   i32x4;
typedef __attribute__((ext_vector_type(8))) short bf16x8;
typedef __attribute__((ext_vector_type(4))) short s16x4;

__device__ __forceinline__ unsigned short f2bf(float f){
  __hip_bfloat16 h = __float2bfloat16(f);   // HW RNE (v_cvt_pk_bf16_f32 when paired)
  return *reinterpret_cast<unsigned short*>(&h);
}

// ---- kernel 0: W [768][128] f32 -> Wt [128][768] bf16, LDS-tiled transpose ----
__global__ __launch_bounds__(256) void k_prep(const float* __restrict__ W,
                                              unsigned short* __restrict__ Wt){
  __shared__ float sT[64][65];
  const int tid = threadIdx.x;
  const int k0 = (blockIdx.x % 12) * 64;
  const int d0 = (blockIdx.x / 12) * 64;
  const int rr = tid >> 4;          // 0..15
  const int cg = tid & 15;          // 0..15 -> 4 cols

  #pragma unroll
  for (int p = 0; p < 4; ++p){
    int k = rr + p*16;
    f32x4 v = *(const f32x4*)&W[(size_t)(k0 + k)*Dn + d0 + cg*4];
    sT[k][cg*4+0] = v[0]; sT[k][cg*4+1] = v[1];
    sT[k][cg*4+2] = v[2]; sT[k][cg*4+3] = v[3];
  }
  __syncthreads();
  #pragma unroll
  for (int p = 0; p < 4; ++p){
    int d = rr + p*16;
    s16x4 t;
    #pragma unroll
    for (int j = 0; j < 4; ++j) t[j] = (short)f2bf(sT[cg*4+j][d]);
    *(s16x4*)&Wt[(size_t)(d0 + d)*Hn + k0 + cg*4] = t;
  }
}

// ---- kernel 1: h = X @ W + b  (bf16 MFMA 16x16x32, fp32 out) ----
// BM=64, BN=128, BK=64. 256 threads = 4 waves. 2-deep register staging pipeline:
// step s: ds_write set holding s+1 -> LDS[cur^1]; issue loads s+3 -> same set;
// compute LDS[cur]. Loads get ~2 compute phases (~1000cy > 900cy HBM) in flight.
// LDS XOR-swizzled (byte ^= (row&7)<<4): conflict-free ds_read_b128 fragments.
__global__ __launch_bounds__(256) void k_gemm(const float* __restrict__ X,
        const unsigned short* __restrict__ Wt, const float* __restrict__ bias,
        float* __restrict__ Hout){
  __shared__ unsigned char sA[2][64*128];    // [row][128B of swizzled bf16 k]
  __shared__ unsigned char sB[2][128*128];   // [col][128B of swizzled bf16 k]
  const int tid  = threadIdx.x;
  const int lane = tid & 63;
  const int wave = tid >> 6;
  const int m0 = blockIdx.x * 64;

  // staging maps
  const int ar = tid >> 2, akq = tid & 3;    // A: row, k-quarter
  const int bc = tid >> 1, bkh = tid & 1;    // B: col, k-half
  const float*          Ap = X  + (size_t)(m0 + ar)*Hn + akq*4;
  const unsigned short* Bp = Wt + (size_t)bc*Hn + bkh*32;

  int aw[4], bw[4];
  #pragma unroll
  for (int c=0;c<4;c++) aw[c] = ar*128 + ((akq*8 + c*32) ^ ((ar&7)<<4));   // 8B chunks
  #pragma unroll
  for (int c=0;c<4;c++) bw[c] = bc*128 + ((bkh*64 + c*16) ^ ((bc&7)<<4));  // 16B chunks

  // fragment read bases
  int abase[4], aswz[4];
  #pragma unroll
  for (int mi=0;mi<4;mi++){
    int row = mi*16 + (lane&15);
    abase[mi] = row*128; aswz[mi] = (row&7)<<4;
  }
  int bbase[2], bswz[2];
  #pragma unroll
  for (int ni=0;ni<2;ni++){
    int col = wave*32 + ni*16 + (lane&15);
    bbase[ni] = col*128; bswz[ni] = (col&7)<<4;
  }
  const int kblk = (lane>>4)*16;

  f32x4 acc[4][2];
  #pragma unroll
  for (int mi=0;mi<4;mi++)
    #pragma unroll
    for (int ni=0;ni<2;ni++) acc[mi][ni] = (f32x4){0.f,0.f,0.f,0.f};

  f32x4 av[2][4]; i32x4 bv[2][4];   // set t&1 holds loads for step t

  // prologue: stage step 0 directly into LDS[0]
  #pragma unroll
  for (int c=0;c<4;c++) av[0][c] = *(const f32x4*)(Ap + c*16);
  #pragma unroll
  for (int c=0;c<4;c++) bv[0][c] = *(const i32x4*)(Bp + c*8);
  #pragma unroll
  for (int c=0;c<4;c++){
    s16x4 t;
    t[0]=(short)f2bf(av[0][c][0]); t[1]=(short)f2bf(av[0][c][1]);
    t[2]=(short)f2bf(av[0][c][2]); t[3]=(short)f2bf(av[0][c][3]);
    *(s16x4*)&sA[0][aw[c]] = t;
  }
  #pragma unroll
  for (int c=0;c<4;c++) *(i32x4*)&sB[0][bw[c]] = bv[0][c];
  // issue loads for step 1 (set 1) and step 2 (set 0)
  #pragma unroll
  for (int c=0;c<4;c++) av[1][c] = *(const f32x4*)(Ap + 64 + c*16);
  #pragma unroll
  for (int c=0;c<4;c++) bv[1][c] = *(const i32x4*)(Bp + 64 + c*8);
  #pragma unroll
  for (int c=0;c<4;c++) av[0][c] = *(const f32x4*)(Ap + 128 + c*16);
  #pragma unroll
  for (int c=0;c<4;c++) bv[0][c] = *(const i32x4*)(Bp + 128 + c*8);
  __syncthreads();

  #pragma unroll
  for (int step=0; step<12; ++step){
    const int cur = step & 1;        // compile-time after unroll
    const int p   = (step+1) & 1;
    if (step < 11){  // convert + write step+1 tile (barrier behind us makes WAR safe)
      #pragma unroll
      for (int c=0;c<4;c++){
        s16x4 t;
        t[0]=(short)f2bf(av[p][c][0]); t[1]=(short)f2bf(av[p][c][1]);
        t[2]=(short)f2bf(av[p][c][2]); t[3]=(short)f2bf(av[p][c][3]);
        *(s16x4*)&sA[cur^1][aw[c]] = t;
      }
      #pragma unroll
      for (int c=0;c<4;c++) *(i32x4*)&sB[cur^1][bw[c]] = bv[p][c];
    }
    if (step < 9){   // issue loads for step+3 into the set just drained
      #pragma unroll
      for (int c=0;c<4;c++) av[p][c] = *(const f32x4*)(Ap + (step+3)*64 + c*16);
      #pragma unroll
      for (int c=0;c<4;c++) bv[p][c] = *(const i32x4*)(Bp + (step+3)*64 + c*8);
    }
    #pragma unroll
    for (int ks=0; ks<2; ++ks){
      bf16x8 af[4], bfv[2];
      #pragma unroll
      for (int mi=0;mi<4;mi++)
        af[mi] = *(const bf16x8*)&sA[cur][abase[mi] + ((ks*64 + kblk) ^ aswz[mi])];
      #pragma unroll
      for (int ni=0;ni<2;ni++)
        bfv[ni] = *(const bf16x8*)&sB[cur][bbase[ni] + ((ks*64 + kblk) ^ bswz[ni])];
      #pragma unroll
      for (int mi=0;mi<4;mi++)
        #pragma unroll
        for (int ni=0;ni<2;ni++)
          acc[mi][ni] = __builtin_amdgcn_mfma_f32_16x16x32_bf16(af[mi], bfv[ni], acc[mi][ni], 0, 0, 0);
    }
    __syncthreads();
  }

  // epilogue: C/D layout col=lane&15, row=(lane>>4)*4+r  (m89-verified)
  #pragma unroll
  for (int ni=0;ni<2;ni++){
    int col = wave*32 + ni*16 + (lane&15);
    float bb = bias[col];
    #pragma unroll
    for (int mi=0;mi<4;mi++){
      int row0 = m0 + mi*16 + (lane>>4)*4;
      #pragma unroll
      for (int r=0;r<4;r++)
        Hout[(size_t)(row0 + r)*Dn + col] = acc[mi][ni][r] + bb;
    }
  }
}

// ---- kernel 2: per-(batch,attr,dim-half) segment mean -> pooled + empty ----
__global__ __launch_bounds__(256) void k_scan(const int* __restrict__ attr,
        const int* __restrict__ item, const float* __restrict__ Hsrc,
        float* __restrict__ pooled, float* __restrict__ empty){
  __shared__ float ssum[4][IT][64];   // 32 KB, one slab per wave
  __shared__ int   slist[4][512];     // 8 KB ordered match lists
  __shared__ int   scnt[IT];

  const int wg  = blockIdx.x;        // (b*8 + a)*2 + dh
  const int dh  = wg & 1;
  const int a   = (wg >> 1) & 7;
  const int b   = wg >> 4;
  const int tid = threadIdx.x;       // 0..255
  const int wv  = tid >> 6;
  const int lane = tid & 63;

  #pragma unroll
  for (int i = 0; i < IT; ++i) ssum[wv][i][lane] = 0.f;
  if (tid < IT) scnt[tid] = 0;

  const int tok0 = wv * 512;
  const int gbase = b * Sn;
  int nm = 0;
  #pragma unroll
  for (int g = 0; g < 8; ++g){
    int tok = tok0 + g*64 + lane;
    int avv = attr[gbase + tok], ivv = item[gbase + tok];
    bool m = (avv == a+1) && (ivv >= 1) && (ivv <= IT);
    unsigned long long mask = __ballot(m);
    int pos = nm + __popcll(mask & ((1ull << lane) - 1ull));
    if (m) slist[wv][pos] = ((ivv-1) << 16) | tok;
    nm += __popcll(mask);
  }
  __syncthreads();   // scnt zeros visible

  for (int e = lane; e < nm; e += 64) atomicAdd(&scnt[slist[wv][e] >> 16], 1);

  const float* hb = Hsrc + (size_t)b*Sn*Dn + dh*64 + lane;
  int e = 0;
  for (; e + 8 <= nm; e += 8){
    int idx[8]; float v[8];
    #pragma unroll
    for (int j=0;j<8;j++) idx[j] = slist[wv][e+j];
    #pragma unroll
    for (int j=0;j<8;j++) v[j] = hb[(size_t)(idx[j] & 0xffff)*Dn];
    #pragma unroll
    for (int j=0;j<8;j++) ssum[wv][idx[j]>>16][lane] += v[j];
  }
  for (; e < nm; ++e){
    int idx = slist[wv][e];
    ssum[wv][idx>>16][lane] += hb[(size_t)(idx & 0xffff)*Dn];
  }
  __syncthreads();

  float* outp = pooled + (size_t)(b*AT + a)*IT*Dn + dh*64;
  for (int o = tid; o < IT*64; o += 256){
    int i = o >> 6, d = o & 63;
    float s = ssum[0][i][d] + ssum[1][i][d] + ssum[2][i][d] + ssum[3][i][d];
    int cnt = scnt[i];
    outp[i*Dn + d] = s / (float)(cnt > 0 ? cnt : 1);
  }
  if (dh == 0 && tid < IT)
    empty[(b*AT + a)*IT + tid] = (scnt[tid] == 0) ? 1.f : 0.f;
}

extern "C" void kernel_launch(void* const* d_in, const int* in_sizes, int n_in,
                              void* d_out, int out_size, void* d_ws, size_t ws_size,
                              hipStream_t stream) {
  const float* hidden = (const float*)d_in[1];
  const int*   attr   = (const int*)  d_in[2];
  const int*   item   = (const int*)  d_in[3];
  const float* W      = (const float*)d_in[4];
  const float* bias   = (const float*)d_in[5];

  float* pooled = (float*)d_out;
  float* empty  = pooled + (size_t)NSEG*Dn;          // +524288
  float* Hout   = empty  + NSEG;                     // +4096

  unsigned short* Wt = (unsigned short*)d_ws;

  k_prep<<<24, 256, 0, stream>>>(W, Wt);
  k_gemm<<<(Bn*Sn)/64, 256, 0, stream>>>(hidden, Wt, bias, Hout);
  k_scan<<<Bn*AT*2, 256, 0, stream>>>(attr, item, Hout, pooled, empty);
}